// Round 1
// baseline (616.265 us; speedup 1.0000x reference)
//
#include <hip/hip_runtime.h>

#define NNODES 100000

// ---------------- edge dtype sniffer (int64 vs int32) ----------------
__global__ void detect_kernel(const int* __restrict__ raw, int* __restrict__ flag) {
    __shared__ int cnt;
    if (threadIdx.x == 0) cnt = 0;
    __syncthreads();
    if (threadIdx.x < 100) {
        // if data is int64, odd int32 words are the (zero) high halves
        if (raw[2 * threadIdx.x + 1] == 0) atomicAdd(&cnt, 1);
    }
    __syncthreads();
    if (threadIdx.x == 0) *flag = (cnt > 50) ? 1 : 0;
}

__global__ void convert_kernel(const int* __restrict__ raw, int* __restrict__ src,
                               int* __restrict__ dst, int E, const int* __restrict__ flag) {
    int e = blockIdx.x * blockDim.x + threadIdx.x;
    if (e >= E) return;
    if (*flag) {                       // int64 storage, little-endian low words
        src[e] = raw[2 * e];
        dst[e] = raw[2 * E + 2 * e];
    } else {                           // int32 storage
        src[e] = raw[e];
        dst[e] = raw[E + e];
    }
}

// ---------------- degree / dinv ----------------
__global__ void degree_kernel(const int* __restrict__ dst, int* __restrict__ indeg, int E) {
    int e = blockIdx.x * blockDim.x + threadIdx.x;
    if (e >= E) return;
    atomicAdd(&indeg[dst[e]], 1);
}

__global__ void dinv_kernel(const int* __restrict__ indeg, float* __restrict__ dinv, int n) {
    int i = blockIdx.x * blockDim.x + threadIdx.x;
    if (i >= n) return;
    dinv[i] = rsqrtf((float)(indeg[i] + 1));   // +1 self loop; always > 0
}

// ---------------- exclusive scan over indeg -> ptr[0..n] ----------------
#define SCAN_T 1024
__global__ void scan_kernel(const int* __restrict__ indeg, int* __restrict__ ptr, int n) {
    __shared__ int part[SCAN_T];
    int t = threadIdx.x;
    int npt = (n + SCAN_T - 1) / SCAN_T;
    int beg = t * npt;
    int end = beg + npt; if (end > n) end = n;
    int s = 0;
    for (int i = beg; i < end && i < n; ++i) s += indeg[i];
    part[t] = s;
    __syncthreads();
    for (int d = 1; d < SCAN_T; d <<= 1) {
        int v = (t >= d) ? part[t - d] : 0;
        __syncthreads();
        part[t] += v;
        __syncthreads();
    }
    int run = (t == 0) ? 0 : part[t - 1];      // exclusive prefix of this chunk
    for (int i = beg; i < end && i < n; ++i) { ptr[i] = run; run += indeg[i]; }
    if (t == SCAN_T - 1) ptr[n] = run;         // == E
}

__global__ void cursor_kernel(const int* __restrict__ ptr, int* __restrict__ cursor, int n) {
    int i = blockIdx.x * blockDim.x + threadIdx.x;
    if (i < n) cursor[i] = ptr[i];
}

__global__ void fill_kernel(const int* __restrict__ src, const int* __restrict__ dst,
                            const float* __restrict__ dinv, int* __restrict__ cursor,
                            int* __restrict__ col, float* __restrict__ wgt, int E) {
    int e = blockIdx.x * blockDim.x + threadIdx.x;
    if (e >= E) return;
    int d = dst[e], s = src[e];
    int pos = atomicAdd(&cursor[d], 1);
    col[pos] = s;
    wgt[pos] = dinv[s];
}

// ---------------- GEMM1: [M,256] @ [256,64] -> [M,64] ----------------
__global__ __launch_bounds__(256) void gemm1_kernel(const float* __restrict__ x,
                                                    const float* __restrict__ W,
                                                    float* __restrict__ H, int M) {
    __shared__ float xs[64][65];
    __shared__ float ws[64][64];
    int tid = threadIdx.x;
    int bm = blockIdx.x * 64;
    int ty = tid >> 4, tx = tid & 15;
    float acc[4][4] = {};
    for (int kt = 0; kt < 256; kt += 64) {
#pragma unroll
        for (int i = 0; i < 4; ++i) {
            int lin = (tid << 2) + i;          // float4 index 0..1023
            int r = lin >> 4;
            int c = (lin & 15) << 2;
            float4 v = make_float4(0.f, 0.f, 0.f, 0.f);
            int gr = bm + r;
            if (gr < M) v = *reinterpret_cast<const float4*>(&x[(size_t)gr * 256 + kt + c]);
            xs[r][c] = v.x; xs[r][c + 1] = v.y; xs[r][c + 2] = v.z; xs[r][c + 3] = v.w;
        }
#pragma unroll
        for (int i = 0; i < 4; ++i) {
            int lin = (tid << 2) + i;
            int r = lin >> 4;
            int c = (lin & 15) << 2;
            *reinterpret_cast<float4*>(&ws[r][c]) =
                *reinterpret_cast<const float4*>(&W[(size_t)(kt + r) * 64 + c]);
        }
        __syncthreads();
#pragma unroll 8
        for (int kk = 0; kk < 64; ++kk) {
            float a[4], b[4];
#pragma unroll
            for (int i = 0; i < 4; ++i) a[i] = xs[ty * 4 + i][kk];
            float4 bv = *reinterpret_cast<const float4*>(&ws[kk][tx << 2]);
            b[0] = bv.x; b[1] = bv.y; b[2] = bv.z; b[3] = bv.w;
#pragma unroll
            for (int i = 0; i < 4; ++i)
#pragma unroll
                for (int j = 0; j < 4; ++j)
                    acc[i][j] = fmaf(a[i], b[j], acc[i][j]);
        }
        __syncthreads();
    }
#pragma unroll
    for (int i = 0; i < 4; ++i) {
        int gr = bm + ty * 4 + i;
        if (gr < M) {
            float4 o; o.x = acc[i][0]; o.y = acc[i][1]; o.z = acc[i][2]; o.w = acc[i][3];
            *reinterpret_cast<float4*>(&H[(size_t)gr * 64 + (tx << 2)]) = o;
        }
    }
}

// ---------------- aggregation: out[i,:] = dinv[i]*(sum_j w[j]*h[col[j],:] + dinv[i]*h[i,:]) ----------------
__global__ __launch_bounds__(256) void aggregate_kernel(const float* __restrict__ h,
                                                        const int* __restrict__ ptr,
                                                        const int* __restrict__ col,
                                                        const float* __restrict__ wgt,
                                                        const float* __restrict__ dinv,
                                                        const float* __restrict__ bias,
                                                        float* __restrict__ out, int n, int relu) {
    int node = (blockIdx.x << 2) + (threadIdx.x >> 6);
    if (node >= n) return;
    int lane = threadIdx.x & 63;
    float di = dinv[node];
    float acc = di * h[(size_t)node * 64 + lane];   // self-loop (di factored out)
    int p = ptr[node];
    int e = ptr[node + 1];
    for (; p + 1 < e; p += 2) {
        int   j0 = col[p],  j1 = col[p + 1];
        float w0 = wgt[p],  w1 = wgt[p + 1];
        float h0 = h[(size_t)j0 * 64 + lane];
        float h1v = h[(size_t)j1 * 64 + lane];
        acc = fmaf(w0, h0, acc);
        acc = fmaf(w1, h1v, acc);
    }
    if (p < e) acc = fmaf(wgt[p], h[(size_t)col[p] * 64 + lane], acc);
    float v = acc * di;
    if (bias) v += bias[lane];
    if (relu) v = fmaxf(v, 0.f);
    out[(size_t)node * 64 + lane] = v;
}

// ---------------- GEMM2: [M,64] @ [64,128] + b -> [M,128] ----------------
__global__ __launch_bounds__(256) void gemm2_kernel(const float* __restrict__ A,
                                                    const float* __restrict__ W,
                                                    const float* __restrict__ bias,
                                                    float* __restrict__ out, int M) {
    __shared__ float as[64][65];
    __shared__ float ws[64][128];
    int tid = threadIdx.x;
    int bm = blockIdx.x * 64;
    int ty = tid >> 4, tx = tid & 15;
#pragma unroll
    for (int i = 0; i < 4; ++i) {
        int lin = (tid << 2) + i;
        int r = lin >> 4;
        int c = (lin & 15) << 2;
        float4 v = make_float4(0.f, 0.f, 0.f, 0.f);
        int gr = bm + r;
        if (gr < M) v = *reinterpret_cast<const float4*>(&A[(size_t)gr * 64 + c]);
        as[r][c] = v.x; as[r][c + 1] = v.y; as[r][c + 2] = v.z; as[r][c + 3] = v.w;
    }
#pragma unroll
    for (int i = 0; i < 8; ++i) {
        int lin = tid + (i << 8);              // 0..2047 float4s
        int r = lin >> 5;
        int c = (lin & 31) << 2;
        *reinterpret_cast<float4*>(&ws[r][c]) =
            *reinterpret_cast<const float4*>(&W[(size_t)r * 128 + c]);
    }
    __syncthreads();
    float acc[4][8] = {};
#pragma unroll 8
    for (int kk = 0; kk < 64; ++kk) {
        float a[4];
#pragma unroll
        for (int i = 0; i < 4; ++i) a[i] = as[ty * 4 + i][kk];
        float b[8];
        float4 b0 = *reinterpret_cast<const float4*>(&ws[kk][tx * 8]);
        float4 b1 = *reinterpret_cast<const float4*>(&ws[kk][tx * 8 + 4]);
        b[0] = b0.x; b[1] = b0.y; b[2] = b0.z; b[3] = b0.w;
        b[4] = b1.x; b[5] = b1.y; b[6] = b1.z; b[7] = b1.w;
#pragma unroll
        for (int i = 0; i < 4; ++i)
#pragma unroll
            for (int j = 0; j < 8; ++j)
                acc[i][j] = fmaf(a[i], b[j], acc[i][j]);
    }
#pragma unroll
    for (int i = 0; i < 4; ++i) {
        int gr = bm + ty * 4 + i;
        if (gr >= M) continue;
#pragma unroll
        for (int jv = 0; jv < 2; ++jv) {
            int cbase = tx * 8 + jv * 4;
            float4 o;
            o.x = acc[i][jv * 4 + 0] + bias[cbase + 0];
            o.y = acc[i][jv * 4 + 1] + bias[cbase + 1];
            o.z = acc[i][jv * 4 + 2] + bias[cbase + 2];
            o.w = acc[i][jv * 4 + 3] + bias[cbase + 3];
            *reinterpret_cast<float4*>(&out[(size_t)gr * 128 + cbase]) = o;
        }
    }
}

extern "C" void kernel_launch(void* const* d_in, const int* in_sizes, int n_in,
                              void* d_out, int out_size, void* d_ws, size_t ws_size,
                              hipStream_t stream) {
    const float* x  = (const float*)d_in[0];
    const int*   ei = (const int*)d_in[1];
    const float* W1 = (const float*)d_in[2];
    const float* b1 = (const float*)d_in[3];
    const float* W2 = (const float*)d_in[4];
    const float* b2 = (const float*)d_in[5];
    float* out = (float*)d_out;
    const int n = NNODES;
    const int E = in_sizes[1] / 2;

    char* w = (char*)d_ws;
    auto alloc = [&](size_t bytes) {
        char* p = w;
        w += (bytes + 255) & ~(size_t)255;
        return p;
    };
    int*   flag   = (int*)  alloc(4);
    int*   src32  = (int*)  alloc((size_t)E * 4);
    int*   dst32  = (int*)  alloc((size_t)E * 4);
    int*   indeg  = (int*)  alloc((size_t)n * 4);
    float* dinv   = (float*)alloc((size_t)n * 4);
    int*   ptr    = (int*)  alloc((size_t)(n + 1) * 4);
    int*   cursor = (int*)  alloc((size_t)n * 4);
    int*   col    = (int*)  alloc((size_t)E * 4);
    float* wgt    = (float*)alloc((size_t)E * 4);
    float* H1     = (float*)alloc((size_t)n * 64 * 4);
    float* h1     = (float*)alloc((size_t)n * 64 * 4);
    float* A2     = H1;   // H1 dead after first aggregation

    hipMemsetAsync(indeg, 0, (size_t)n * 4, stream);

    int eb = (E + 255) / 256;
    int nb = (n + 255) / 256;
    detect_kernel<<<1, 128, 0, stream>>>(ei, flag);
    convert_kernel<<<eb, 256, 0, stream>>>(ei, src32, dst32, E, flag);
    degree_kernel<<<eb, 256, 0, stream>>>(dst32, indeg, E);
    dinv_kernel<<<nb, 256, 0, stream>>>(indeg, dinv, n);
    scan_kernel<<<1, SCAN_T, 0, stream>>>(indeg, ptr, n);
    cursor_kernel<<<nb, 256, 0, stream>>>(ptr, cursor, n);
    fill_kernel<<<eb, 256, 0, stream>>>(src32, dst32, dinv, cursor, col, wgt, E);

    gemm1_kernel<<<(n + 63) / 64, 256, 0, stream>>>(x, W1, H1, n);
    aggregate_kernel<<<(n + 3) / 4, 256, 0, stream>>>(H1, ptr, col, wgt, dinv, b1, h1, n, 1);
    aggregate_kernel<<<(n + 3) / 4, 256, 0, stream>>>(h1, ptr, col, wgt, dinv, nullptr, A2, n, 0);
    gemm2_kernel<<<(n + 63) / 64, 256, 0, stream>>>(A2, W2, b2, out, n);
}

// Round 2
// 461.119 us; speedup vs baseline: 1.3365x; 1.3365x over previous
//
#include <hip/hip_runtime.h>

#define NNODES 100000
#define SCAN_ELEMS 1024   // elements per scan block (256 threads x 4)

// ---------------- edge dtype sniffer (int64 vs int32) ----------------
__global__ void detect_kernel(const int* __restrict__ raw, int* __restrict__ flag) {
    __shared__ int cnt;
    if (threadIdx.x == 0) cnt = 0;
    __syncthreads();
    if (threadIdx.x < 100) {
        // if data is int64, odd int32 words are the (zero) high halves
        if (raw[2 * threadIdx.x + 1] == 0) atomicAdd(&cnt, 1);
    }
    __syncthreads();
    if (threadIdx.x == 0) *flag = (cnt > 50) ? 1 : 0;
}

// convert to int32 src/dst AND accumulate in-degree in one pass
__global__ void convert_degree_kernel(const int* __restrict__ raw, int* __restrict__ src,
                                      int* __restrict__ dst, int* __restrict__ indeg,
                                      int E, const int* __restrict__ flag) {
    int e = blockIdx.x * blockDim.x + threadIdx.x;
    if (e >= E) return;
    int s, d;
    if (*flag) {                       // int64 storage, little-endian low words
        s = raw[2 * e];
        d = raw[2 * E + 2 * e];
    } else {                           // int32 storage
        s = raw[e];
        d = raw[E + e];
    }
    src[e] = s;
    dst[e] = d;
    atomicAdd(&indeg[d], 1);
}

__global__ void dinv_kernel(const int* __restrict__ indeg, float* __restrict__ dinv, int n) {
    int i = blockIdx.x * blockDim.x + threadIdx.x;
    if (i >= n) return;
    dinv[i] = rsqrtf((float)(indeg[i] + 1));   // +1 self loop; always > 0
}

// ---------------- device-wide exclusive scan: indeg -> ptr[0..n] ----------------
__global__ __launch_bounds__(256) void scan_partial_kernel(const int* __restrict__ indeg,
                                                           int* __restrict__ bsum, int n) {
    int base = blockIdx.x * SCAN_ELEMS + threadIdx.x * 4;
    int s = 0;
    if (base + 3 < n) {
        int4 v = *reinterpret_cast<const int4*>(&indeg[base]);
        s = v.x + v.y + v.z + v.w;
    } else {
        for (int i = base; i < n && i < base + 4; ++i) s += indeg[i];
    }
#pragma unroll
    for (int d = 32; d; d >>= 1) s += __shfl_down(s, d, 64);
    __shared__ int ws[4];
    int wid = threadIdx.x >> 6;
    if ((threadIdx.x & 63) == 0) ws[wid] = s;
    __syncthreads();
    if (threadIdx.x == 0) bsum[blockIdx.x] = ws[0] + ws[1] + ws[2] + ws[3];
}

// nb <= 128 partials; also writes ptr[n] = total edge count
__global__ void scan_partials_kernel(const int* __restrict__ bsum, int* __restrict__ boff,
                                     int* __restrict__ ptr_n, int nb) {
    __shared__ int s[128];
    int t = threadIdx.x;
    s[t] = (t < nb) ? bsum[t] : 0;
    __syncthreads();
    for (int d = 1; d < 128; d <<= 1) {
        int v = (t >= d) ? s[t - d] : 0;
        __syncthreads();
        s[t] += v;
        __syncthreads();
    }
    if (t < nb) boff[t] = (t == 0) ? 0 : s[t - 1];
    if (t == 127) *ptr_n = s[127];
}

__global__ __launch_bounds__(256) void scan_write_kernel(const int* __restrict__ indeg,
                                                         const int* __restrict__ boff,
                                                         int* __restrict__ ptr, int n) {
    __shared__ int ts[256];
    int base = blockIdx.x * SCAN_ELEMS + threadIdx.x * 4;
    int v0 = 0, v1 = 0, v2 = 0, v3 = 0;
    if (base + 3 < n) {
        int4 v = *reinterpret_cast<const int4*>(&indeg[base]);
        v0 = v.x; v1 = v.y; v2 = v.z; v3 = v.w;
    } else {
        if (base < n)     v0 = indeg[base];
        if (base + 1 < n) v1 = indeg[base + 1];
        if (base + 2 < n) v2 = indeg[base + 2];
    }
    ts[threadIdx.x] = v0 + v1 + v2 + v3;
    __syncthreads();
    for (int d = 1; d < 256; d <<= 1) {
        int t = (threadIdx.x >= d) ? ts[threadIdx.x - d] : 0;
        __syncthreads();
        ts[threadIdx.x] += t;
        __syncthreads();
    }
    int run = boff[blockIdx.x] + ((threadIdx.x == 0) ? 0 : ts[threadIdx.x - 1]);
    if (base < n)     { ptr[base] = run;     run += v0; }
    if (base + 1 < n) { ptr[base + 1] = run; run += v1; }
    if (base + 2 < n) { ptr[base + 2] = run; run += v2; }
    if (base + 3 < n) { ptr[base + 3] = run; }
}

__global__ void cursor_kernel(const int* __restrict__ ptr, int* __restrict__ cursor, int n) {
    int i = blockIdx.x * blockDim.x + threadIdx.x;
    if (i < n) cursor[i] = ptr[i];
}

__global__ void fill_kernel(const int* __restrict__ src, const int* __restrict__ dst,
                            const float* __restrict__ dinv, int* __restrict__ cursor,
                            int* __restrict__ col, float* __restrict__ wgt, int E) {
    int e = blockIdx.x * blockDim.x + threadIdx.x;
    if (e >= E) return;
    int d = dst[e], s = src[e];
    int pos = atomicAdd(&cursor[d], 1);
    col[pos] = s;
    wgt[pos] = dinv[s];
}

// ---------------- GEMM1: [M,256] @ [256,64] -> [M,64] ----------------
__global__ __launch_bounds__(256) void gemm1_kernel(const float* __restrict__ x,
                                                    const float* __restrict__ W,
                                                    float* __restrict__ H, int M) {
    __shared__ float xs[64][65];
    __shared__ float ws[64][64];
    int tid = threadIdx.x;
    int bm = blockIdx.x * 64;
    int ty = tid >> 4, tx = tid & 15;
    float acc[4][4] = {};
    for (int kt = 0; kt < 256; kt += 64) {
#pragma unroll
        for (int i = 0; i < 4; ++i) {
            int lin = (tid << 2) + i;          // float4 index 0..1023
            int r = lin >> 4;
            int c = (lin & 15) << 2;
            float4 v = make_float4(0.f, 0.f, 0.f, 0.f);
            int gr = bm + r;
            if (gr < M) v = *reinterpret_cast<const float4*>(&x[(size_t)gr * 256 + kt + c]);
            xs[r][c] = v.x; xs[r][c + 1] = v.y; xs[r][c + 2] = v.z; xs[r][c + 3] = v.w;
        }
#pragma unroll
        for (int i = 0; i < 4; ++i) {
            int lin = (tid << 2) + i;
            int r = lin >> 4;
            int c = (lin & 15) << 2;
            *reinterpret_cast<float4*>(&ws[r][c]) =
                *reinterpret_cast<const float4*>(&W[(size_t)(kt + r) * 64 + c]);
        }
        __syncthreads();
#pragma unroll 8
        for (int kk = 0; kk < 64; ++kk) {
            float a[4], b[4];
#pragma unroll
            for (int i = 0; i < 4; ++i) a[i] = xs[ty * 4 + i][kk];
            float4 bv = *reinterpret_cast<const float4*>(&ws[kk][tx << 2]);
            b[0] = bv.x; b[1] = bv.y; b[2] = bv.z; b[3] = bv.w;
#pragma unroll
            for (int i = 0; i < 4; ++i)
#pragma unroll
                for (int j = 0; j < 4; ++j)
                    acc[i][j] = fmaf(a[i], b[j], acc[i][j]);
        }
        __syncthreads();
    }
#pragma unroll
    for (int i = 0; i < 4; ++i) {
        int gr = bm + ty * 4 + i;
        if (gr < M) {
            float4 o; o.x = acc[i][0]; o.y = acc[i][1]; o.z = acc[i][2]; o.w = acc[i][3];
            *reinterpret_cast<float4*>(&H[(size_t)gr * 64 + (tx << 2)]) = o;
        }
    }
}

// ---------------- aggregation: out[i,:] = dinv[i]*(sum_j w[j]*h[col[j],:] + dinv[i]*h[i,:]) ----------------
__global__ __launch_bounds__(256) void aggregate_kernel(const float* __restrict__ h,
                                                        const int* __restrict__ ptr,
                                                        const int* __restrict__ col,
                                                        const float* __restrict__ wgt,
                                                        const float* __restrict__ dinv,
                                                        const float* __restrict__ bias,
                                                        float* __restrict__ out, int n, int relu) {
    int node = (blockIdx.x << 2) + (threadIdx.x >> 6);
    if (node >= n) return;
    int lane = threadIdx.x & 63;
    float di = dinv[node];
    float acc = di * h[(size_t)node * 64 + lane];   // self-loop (di factored out)
    int p = ptr[node];
    int e = ptr[node + 1];
    for (; p + 1 < e; p += 2) {
        int   j0 = col[p],  j1 = col[p + 1];
        float w0 = wgt[p],  w1 = wgt[p + 1];
        float h0 = h[(size_t)j0 * 64 + lane];
        float h1v = h[(size_t)j1 * 64 + lane];
        acc = fmaf(w0, h0, acc);
        acc = fmaf(w1, h1v, acc);
    }
    if (p < e) acc = fmaf(wgt[p], h[(size_t)col[p] * 64 + lane], acc);
    float v = acc * di;
    if (bias) v += bias[lane];
    if (relu) v = fmaxf(v, 0.f);
    out[(size_t)node * 64 + lane] = v;
}

// ---------------- GEMM2: [M,64] @ [64,128] + b -> [M,128] ----------------
__global__ __launch_bounds__(256) void gemm2_kernel(const float* __restrict__ A,
                                                    const float* __restrict__ W,
                                                    const float* __restrict__ bias,
                                                    float* __restrict__ out, int M) {
    __shared__ float as[64][65];
    __shared__ float ws[64][128];
    int tid = threadIdx.x;
    int bm = blockIdx.x * 64;
    int ty = tid >> 4, tx = tid & 15;
#pragma unroll
    for (int i = 0; i < 4; ++i) {
        int lin = (tid << 2) + i;
        int r = lin >> 4;
        int c = (lin & 15) << 2;
        float4 v = make_float4(0.f, 0.f, 0.f, 0.f);
        int gr = bm + r;
        if (gr < M) v = *reinterpret_cast<const float4*>(&A[(size_t)gr * 64 + c]);
        as[r][c] = v.x; as[r][c + 1] = v.y; as[r][c + 2] = v.z; as[r][c + 3] = v.w;
    }
#pragma unroll
    for (int i = 0; i < 8; ++i) {
        int lin = tid + (i << 8);              // 0..2047 float4s
        int r = lin >> 5;
        int c = (lin & 31) << 2;
        *reinterpret_cast<float4*>(&ws[r][c]) =
            *reinterpret_cast<const float4*>(&W[(size_t)r * 128 + c]);
    }
    __syncthreads();
    float acc[4][8] = {};
#pragma unroll 8
    for (int kk = 0; kk < 64; ++kk) {
        float a[4];
#pragma unroll
        for (int i = 0; i < 4; ++i) a[i] = as[ty * 4 + i][kk];
        float b[8];
        float4 b0 = *reinterpret_cast<const float4*>(&ws[kk][tx * 8]);
        float4 b1 = *reinterpret_cast<const float4*>(&ws[kk][tx * 8 + 4]);
        b[0] = b0.x; b[1] = b0.y; b[2] = b0.z; b[3] = b0.w;
        b[4] = b1.x; b[5] = b1.y; b[6] = b1.z; b[7] = b1.w;
#pragma unroll
        for (int i = 0; i < 4; ++i)
#pragma unroll
            for (int j = 0; j < 8; ++j)
                acc[i][j] = fmaf(a[i], b[j], acc[i][j]);
    }
#pragma unroll
    for (int i = 0; i < 4; ++i) {
        int gr = bm + ty * 4 + i;
        if (gr >= M) continue;
#pragma unroll
        for (int jv = 0; jv < 2; ++jv) {
            int cbase = tx * 8 + jv * 4;
            float4 o;
            o.x = acc[i][jv * 4 + 0] + bias[cbase + 0];
            o.y = acc[i][jv * 4 + 1] + bias[cbase + 1];
            o.z = acc[i][jv * 4 + 2] + bias[cbase + 2];
            o.w = acc[i][jv * 4 + 3] + bias[cbase + 3];
            *reinterpret_cast<float4*>(&out[(size_t)gr * 128 + cbase]) = o;
        }
    }
}

extern "C" void kernel_launch(void* const* d_in, const int* in_sizes, int n_in,
                              void* d_out, int out_size, void* d_ws, size_t ws_size,
                              hipStream_t stream) {
    const float* x  = (const float*)d_in[0];
    const int*   ei = (const int*)d_in[1];
    const float* W1 = (const float*)d_in[2];
    const float* b1 = (const float*)d_in[3];
    const float* W2 = (const float*)d_in[4];
    const float* b2 = (const float*)d_in[5];
    float* out = (float*)d_out;
    const int n = NNODES;
    const int E = in_sizes[1] / 2;

    char* w = (char*)d_ws;
    auto alloc = [&](size_t bytes) {
        char* p = w;
        w += (bytes + 255) & ~(size_t)255;
        return p;
    };
    int*   flag   = (int*)  alloc(4);
    int*   src32  = (int*)  alloc((size_t)E * 4);
    int*   dst32  = (int*)  alloc((size_t)E * 4);
    int*   indeg  = (int*)  alloc((size_t)n * 4);
    float* dinv   = (float*)alloc((size_t)n * 4);
    int*   ptr    = (int*)  alloc((size_t)(n + 1) * 4);
    int*   cursor = (int*)  alloc((size_t)n * 4);
    int*   bsum   = (int*)  alloc(128 * 4);
    int*   boff   = (int*)  alloc(128 * 4);
    int*   col    = (int*)  alloc((size_t)E * 4);
    float* wgt    = (float*)alloc((size_t)E * 4);
    float* H1     = (float*)alloc((size_t)n * 64 * 4);
    float* h1     = (float*)alloc((size_t)n * 64 * 4);
    float* A2     = H1;   // H1 dead after first aggregation

    hipMemsetAsync(indeg, 0, (size_t)n * 4, stream);

    int eb = (E + 255) / 256;
    int nb = (n + 255) / 256;
    int sb = (n + SCAN_ELEMS - 1) / SCAN_ELEMS;   // 98 scan blocks
    detect_kernel<<<1, 128, 0, stream>>>(ei, flag);
    convert_degree_kernel<<<eb, 256, 0, stream>>>(ei, src32, dst32, indeg, E, flag);
    dinv_kernel<<<nb, 256, 0, stream>>>(indeg, dinv, n);
    scan_partial_kernel<<<sb, 256, 0, stream>>>(indeg, bsum, n);
    scan_partials_kernel<<<1, 128, 0, stream>>>(bsum, boff, &ptr[n], sb);
    scan_write_kernel<<<sb, 256, 0, stream>>>(indeg, boff, ptr, n);
    cursor_kernel<<<nb, 256, 0, stream>>>(ptr, cursor, n);
    fill_kernel<<<eb, 256, 0, stream>>>(src32, dst32, dinv, cursor, col, wgt, E);

    gemm1_kernel<<<(n + 63) / 64, 256, 0, stream>>>(x, W1, H1, n);
    aggregate_kernel<<<(n + 3) / 4, 256, 0, stream>>>(H1, ptr, col, wgt, dinv, b1, h1, n, 1);
    aggregate_kernel<<<(n + 3) / 4, 256, 0, stream>>>(h1, ptr, col, wgt, dinv, nullptr, A2, n, 0);
    gemm2_kernel<<<(n + 63) / 64, 256, 0, stream>>>(A2, W2, b2, out, n);
}